// Round 6
// baseline (193.156 us; speedup 1.0000x reference)
//
#include <hip/hip_runtime.h>

// ---------------------------------------------------------------------------
// 4-layer fused LSTM (UNITS=3) + Dense(1), B=8192, T=256.
//
// R5 changes (from 69 µs / VALUBusy 75% / trans = 2/3 of issue):
//  1. Fused rational cell: one rcp for cn, one for hn (10 -> 7 trans/step).
//     cn = [c*(1+I)(1+G) + (G-1)(1+F)] / [(1+F)(1+I)(1+G)]
//     hn = (C-1) / [(1+O)(1+C)],  C = exp2(2*log2e*cn)  (Carg clamped at 80
//     -> tanh saturates to exactly 1.0f, kills the inf*0 NaN path).
//  2. Two independent batch elements per lane (shared weight regs): 1024
//     waves = 1/SIMD, but 2 interleaved recurrences fill trans-latency
//     bubbles in-wave (ILP > TLP for a fixed-work issue-bound stream).
//
// Layout per 16-lane row (now a PAIR of elements): quad q owns layer q+1,
// lane u owns hidden unit u (u=3 spare). h handoff: quad_perm bcast +
// row_shr:4. Wave-synchronous, no LDS, no barriers.
// ---------------------------------------------------------------------------

#if __has_builtin(__builtin_amdgcn_rcpf)
__device__ __forceinline__ float frcp(float x) { return __builtin_amdgcn_rcpf(x); }
#else
__device__ __forceinline__ float frcp(float x) { return 1.0f / x; }
#endif

#if __has_builtin(__builtin_amdgcn_exp2f)
__device__ __forceinline__ float fexp2(float x) { return __builtin_amdgcn_exp2f(x); }
#else
__device__ __forceinline__ float fexp2(float x) { return exp2f(x); }
#endif

#define LOG2E 1.44269504088896340736f
#define KTWO  (2.0f * LOG2E)

// Broadcast lane (quad_base + K) to all 4 lanes of its quad.
template<int K>
__device__ __forceinline__ float bcast4(float v) {
#if __has_builtin(__builtin_amdgcn_mov_dpp)
    int i = __builtin_amdgcn_mov_dpp(__float_as_int(v), K * 0x55, 0xF, 0xF, true);
    return __int_as_float(i);
#else
    return __shfl(v, (int)((threadIdx.x & ~3u) | K), 64);
#endif
}

// Shift 4 lanes toward higher IDs within each 16-lane row; lanes 0-3 of each
// row receive 0 (bound_ctrl). DPP ctrl ROW_SHR:4 = 0x114.
__device__ __forceinline__ float shr4(float v) {
#if __has_builtin(__builtin_amdgcn_mov_dpp)
    int i = __builtin_amdgcn_mov_dpp(__float_as_int(v), 0x114, 0xF, 0xF, true);
    return __int_as_float(i);
#else
    float r = __shfl(v, (int)(threadIdx.x & 15u) - 4, 16);
    return ((threadIdx.x & 15u) >= 4) ? r : 0.0f;
#endif
}

// One pipelined step for BOTH chains. Weights shared; all indices static.
// MASK: pipeline-fill masking (quad q idle until n >= q).
template<bool MASK>
__device__ __forceinline__ void step2(int n, float xa, float xb, int q,
                                      const float (&W)[3][4], const float (&U)[3][4],
                                      const float (&Bv)[4],
                                      float (&h)[2][3], float (&xin)[2][3],
                                      float (&c)[2])
{
    float z[2][4];
#pragma unroll
    for (int k = 0; k < 2; ++k) {
        const float xs = k ? xb : xa;
        const float x0 = (q == 0) ? xs : xin[k][0];   // quad0's xin[0] is 0
#pragma unroll
        for (int g = 0; g < 4; ++g) {
            float zz = Bv[g];
            zz = fmaf(x0,        W[0][g], zz);
            zz = fmaf(xin[k][1], W[1][g], zz);        // 0 for quad 0
            zz = fmaf(xin[k][2], W[2][g], zz);
            zz = fmaf(h[k][0],   U[0][g], zz);
            zz = fmaf(h[k][1],   U[1][g], zz);
            zz = fmaf(h[k][2],   U[2][g], zz);
            z[k][g] = zz;
        }
    }
#pragma unroll
    for (int k = 0; k < 2; ++k) {
        // Folded exps: I,F,O = e^{-z_gate}; G = e^{2*z_g}.
        const float I = fexp2(z[k][0]);
        const float F = fexp2(z[k][1]);
        const float G = fexp2(z[k][2]);
        const float O = fexp2(z[k][3]);
        const float DI = 1.0f + I, DF = 1.0f + F, DG = 1.0f + G, DO = 1.0f + O;
        // cn = sig(zf)*c + sig(zi)*tanh(zg), single rcp:
        const float PIG = DI * DG;
        const float num = fmaf(c[k], PIG, (G - 1.0f) * DF);
        float cn = num * frcp(PIG * DF);
        // hn = sig(zo)*tanh(cn), single rcp. Clamp exp2 arg: tanh -> 1.0f
        // exactly for cn > 27.7, and avoids inf*0 = NaN in the fused form.
        float Carg = KTWO * cn;
        Carg = fminf(Carg, 80.0f);
        const float C = fexp2(Carg);
        float hn = (C - 1.0f) * frcp(DO * (1.0f + C));
        if (MASK) {                 // fill: quad q idle until n >= q
            const bool v = (n >= q);
            cn = v ? cn : c[k];     // c was 0 -> stays 0
            hn = v ? hn : 0.0f;
        }
        c[k] = cn;
        const float hb0 = bcast4<0>(hn);
        const float hb1 = bcast4<1>(hn);
        const float hb2 = bcast4<2>(hn);
        h[k][0] = hb0; h[k][1] = hb1; h[k][2] = hb2;  // own hidden, next t
        xin[k][0] = shr4(hb0);                         // deliver to next quad
        xin[k][1] = shr4(hb1);
        xin[k][2] = shr4(hb2);
    }
}

__global__ __launch_bounds__(128) void lstm_pipe2(
    const float* __restrict__ state,
    const float* __restrict__ w1, const float* __restrict__ u1, const float* __restrict__ b1,
    const float* __restrict__ w2, const float* __restrict__ u2, const float* __restrict__ b2,
    const float* __restrict__ w3, const float* __restrict__ u3, const float* __restrict__ b3,
    const float* __restrict__ w4, const float* __restrict__ u4, const float* __restrict__ b4,
    const float* __restrict__ wd, const float* __restrict__ bd,
    float* __restrict__ out, int B)
{
    const int tid = blockIdx.x * 128 + threadIdx.x;
    const int p = tid >> 4;               // element PAIR per 16-lane row
    if (p >= ((B + 1) >> 1)) return;
    const int e0 = 2 * p;
    const int e1 = e0 + 1;
    const bool has1 = (e1 < B);
    const int l16 = tid & 15;
    const int q = l16 >> 2;               // quad = layer index 0..3
    const int u = l16 & 3;                // unit within layer (3 = spare)
    const int uu = (u < 3) ? u : 2;

    const float* Wp = (q == 0) ? w1 : (q == 1) ? w2 : (q == 2) ? w3 : w4;
    const float* Up = (q == 0) ? u1 : (q == 1) ? u2 : (q == 2) ? u3 : u4;
    const float* Bp = (q == 0) ? b1 : (q == 1) ? b2 : (q == 2) ? b3 : b4;
    const int nx = (q == 0) ? 1 : 3;      // input dims of this layer

    // Folded activation scales per gate (i,f,o: -log2e; g: +2*log2e).
    float W[3][4], U[3][4], Bv[4];
#pragma unroll
    for (int g = 0; g < 4; ++g) {
        const float sc = (g == 2) ? (2.0f * LOG2E) : (-LOG2E);
        const int col = g * 3 + uu;       // gate-major columns
        Bv[g] = Bp[col] * sc;
#pragma unroll
        for (int k = 0; k < 3; ++k) {
            W[k][g] = (k < nx) ? Wp[k * 12 + col] * sc : 0.0f;
            U[k][g] = Up[k * 12 + col] * sc;
        }
    }

    float h[2][3]   = {{0.f,0.f,0.f},{0.f,0.f,0.f}};
    float xin[2][3] = {{0.f,0.f,0.f},{0.f,0.f,0.f}};
    float c[2] = {0.f, 0.f};

    const float4* sp0 = reinterpret_cast<const float4*>(state + (size_t)e0 * 256);
    const float4* sp1 = reinterpret_cast<const float4*>(state + (size_t)(has1 ? e1 : e0) * 256);

    // --- pipeline fill: n = 0,1,2 (masked), n = 3 (first fully-valid) ---
    float4 wa = sp0[0], wb = sp1[0];
    step2<true >(0, wa.x, wb.x, q, W, U, Bv, h, xin, c);
    step2<true >(1, wa.y, wb.y, q, W, U, Bv, h, xin, c);
    step2<true >(2, wa.z, wb.z, q, W, U, Bv, h, xin, c);
    float4 na = sp0[1], nb = sp1[1];      // prefetch word 1
    step2<false>(3, wa.w, wb.w, q, W, U, Bv, h, xin, c);
    wa = na; wb = nb;

    // --- main loop: words 1..62, prefetch one word ahead ---
    for (int g4 = 1; g4 < 63; ++g4) {
        na = sp0[g4 + 1]; nb = sp1[g4 + 1];
        step2<false>(0, wa.x, wb.x, q, W, U, Bv, h, xin, c);
        step2<false>(0, wa.y, wb.y, q, W, U, Bv, h, xin, c);
        step2<false>(0, wa.z, wb.z, q, W, U, Bv, h, xin, c);
        step2<false>(0, wa.w, wb.w, q, W, U, Bv, h, xin, c);
        wa = na; wb = nb;
    }
    // --- word 63 (t = 252..255) ---
    step2<false>(0, wa.x, wb.x, q, W, U, Bv, h, xin, c);
    step2<false>(0, wa.y, wb.y, q, W, U, Bv, h, xin, c);
    step2<false>(0, wa.z, wb.z, q, W, U, Bv, h, xin, c);
    step2<false>(0, wa.w, wb.w, q, W, U, Bv, h, xin, c);

    // --- drain: n = 256,257,258 — finishes quads 1..3; x forced to 0 ---
    step2<false>(0, 0.f, 0.f, q, W, U, Bv, h, xin, c);
    step2<false>(0, 0.f, 0.f, q, W, U, Bv, h, xin, c);
    step2<false>(0, 0.f, 0.f, q, W, U, Bv, h, xin, c);

    // Dense(1): quad 3 holds final h4 (broadcast across its lanes).
    if (l16 == 12) {
        out[e0] = fmaf(h[0][0], wd[0], fmaf(h[0][1], wd[1], fmaf(h[0][2], wd[2], bd[0])));
        if (has1)
            out[e1] = fmaf(h[1][0], wd[0], fmaf(h[1][1], wd[1], fmaf(h[1][2], wd[2], bd[0])));
    }
}

extern "C" void kernel_launch(void* const* d_in, const int* in_sizes, int n_in,
                              void* d_out, int out_size, void* d_ws, size_t ws_size,
                              hipStream_t stream) {
    const float* state = (const float*)d_in[0];
    const float* w1 = (const float*)d_in[1];
    const float* u1 = (const float*)d_in[2];
    const float* b1 = (const float*)d_in[3];
    const float* w2 = (const float*)d_in[4];
    const float* u2 = (const float*)d_in[5];
    const float* b2 = (const float*)d_in[6];
    const float* w3 = (const float*)d_in[7];
    const float* u3 = (const float*)d_in[8];
    const float* b3 = (const float*)d_in[9];
    const float* w4 = (const float*)d_in[10];
    const float* u4 = (const float*)d_in[11];
    const float* b4 = (const float*)d_in[12];
    const float* wd = (const float*)d_in[13];
    const float* bd = (const float*)d_in[14];
    float* out = (float*)d_out;

    const int B = in_sizes[0] / 256;               // 8192
    const int pairs = (B + 1) >> 1;                // 4096
    const long long threads = (long long)pairs * 16;
    const int grid = (int)((threads + 127) / 128); // 512 blocks of 128
    lstm_pipe2<<<grid, 128, 0, stream>>>(state, w1, u1, b1, w2, u2, b2,
                                         w3, u3, b3, w4, u4, b4, wd, bd, out, B);
}

// Round 10
// 142.056 us; speedup vs baseline: 1.3597x; 1.3597x over previous
//
#include <hip/hip_runtime.h>

// ---------------------------------------------------------------------------
// 4-layer fused LSTM (UNITS=3) + Dense(1), B=8192, T=256.
//
// R6 = R4's proven 16-lane/element pipeline (2048 waves, 75% VALUBusy)
//      + R5's proven fused rational cell (7 trans/step instead of 10).
// R5's 2-elements-per-row pairing (1024 waves) is REVERTED: it halved
// occupancy and dropped VALUBusy to 43% (latency-bound).
//
// Layout: 16 lanes (one DPP row) per batch element; quad q owns layer q+1,
// lane u owns hidden unit u (u=3 spare). Iteration n: quad q does t = n-q.
// h handoff: quad_perm bcast + row_shr:4 (wave-synchronous, no LDS).
//
// Fused cell (single rcp for cn, single rcp+exp for hn):
//   I,F,O = exp2(-log2e*z_gate), G = exp2(2*log2e*z_g)  (scales folded into
//   weight registers at load time)
//   cn = c/(1+F) + (G-1)/[(1+I)(1+G)]   computed as one rational: single rcp
//   hn = (C-1) / [(1+O)(1+C)],  C = exp2(min(2*log2e*cn, 80))
//   (clamp -> tanh saturates to exactly 1, kills the inf/inf NaN path)
// ---------------------------------------------------------------------------

#if __has_builtin(__builtin_amdgcn_rcpf)
__device__ __forceinline__ float frcp(float x) { return __builtin_amdgcn_rcpf(x); }
#else
__device__ __forceinline__ float frcp(float x) { return 1.0f / x; }
#endif

#if __has_builtin(__builtin_amdgcn_exp2f)
__device__ __forceinline__ float fexp2(float x) { return __builtin_amdgcn_exp2f(x); }
#else
__device__ __forceinline__ float fexp2(float x) { return exp2f(x); }
#endif

#define LOG2E 1.44269504088896340736f
#define KTWO  (2.0f * LOG2E)

// Broadcast lane (quad_base + K) to all 4 lanes of its quad.
template<int K>
__device__ __forceinline__ float bcast4(float v) {
#if __has_builtin(__builtin_amdgcn_mov_dpp)
    int i = __builtin_amdgcn_mov_dpp(__float_as_int(v), K * 0x55, 0xF, 0xF, true);
    return __int_as_float(i);
#else
    return __shfl(v, (int)((threadIdx.x & ~3u) | K), 64);
#endif
}

// Shift 4 lanes toward higher IDs within each 16-lane row; lanes 0-3 of each
// row receive 0 (bound_ctrl). DPP ctrl ROW_SHR:4 = 0x114.
__device__ __forceinline__ float shr4(float v) {
#if __has_builtin(__builtin_amdgcn_mov_dpp)
    int i = __builtin_amdgcn_mov_dpp(__float_as_int(v), 0x114, 0xF, 0xF, true);
    return __int_as_float(i);
#else
    float r = __shfl(v, (int)(threadIdx.x & 15u) - 4, 16);
    return ((threadIdx.x & 15u) >= 4) ? r : 0.0f;
#endif
}

// One pipelined step. All lanes convergent; per-lane weights encode
// (layer, unit) with folded activation scales.
// MASK: pipeline-fill masking (quad q idle until n >= q).
template<bool MASK>
__device__ __forceinline__ void step(int n, float xs, int q,
                                     const float (&W)[3][4], const float (&U)[3][4],
                                     const float (&Bv)[4],
                                     float (&h)[3], float (&xin)[3], float &c)
{
    // Quad 0's live input is the scalar x (its shr4-fed xin[0] is always 0).
    const float x0 = (q == 0) ? xs : xin[0];
    float z[4];
#pragma unroll
    for (int g = 0; g < 4; ++g) {
        float zz = Bv[g];
        zz = fmaf(x0,     W[0][g], zz);
        zz = fmaf(xin[1], W[1][g], zz);   // 0 for quad 0 (W rows zeroed)
        zz = fmaf(xin[2], W[2][g], zz);
        zz = fmaf(h[0],   U[0][g], zz);
        zz = fmaf(h[1],   U[1][g], zz);
        zz = fmaf(h[2],   U[2][g], zz);
        z[g] = zz;
    }
    // Folded exps: I,F,O = e^{-z_gate}; G = e^{2*z_g}. All 4 independent.
    const float I = fexp2(z[0]);
    const float F = fexp2(z[1]);
    const float G = fexp2(z[2]);
    const float O = fexp2(z[3]);
    const float DI = 1.0f + I, DF = 1.0f + F, DG = 1.0f + G, DO = 1.0f + O;
    // cn = sig(zf)*c + sig(zi)*tanh(zg) = c/DF + (G-1)/(DI*DG), single rcp:
    const float PIG = DI * DG;
    const float num = fmaf(c, PIG, (G - 1.0f) * DF);
    float cn = num * frcp(PIG * DF);
    // hn = sig(zo)*tanh(cn), single rcp; clamp keeps C finite (tanh -> 1).
    float Carg = KTWO * cn;
    Carg = fminf(Carg, 80.0f);
    const float C = fexp2(Carg);
    float hn = (C - 1.0f) * frcp(DO * (1.0f + C));
    if (MASK) {                     // fill: quad q idle until n >= q
        const bool v = (n >= q);
        cn = v ? cn : c;            // c was 0 -> stays 0
        hn = v ? hn : 0.0f;
    }
    c = cn;
    const float hb0 = bcast4<0>(hn);
    const float hb1 = bcast4<1>(hn);
    const float hb2 = bcast4<2>(hn);
    h[0] = hb0; h[1] = hb1; h[2] = hb2;   // own hidden for next t
    xin[0] = shr4(hb0);                    // deliver to next quad
    xin[1] = shr4(hb1);
    xin[2] = shr4(hb2);
}

__global__ __launch_bounds__(256) void lstm_pipe(
    const float* __restrict__ state,
    const float* __restrict__ w1, const float* __restrict__ u1, const float* __restrict__ b1,
    const float* __restrict__ w2, const float* __restrict__ u2, const float* __restrict__ b2,
    const float* __restrict__ w3, const float* __restrict__ u3, const float* __restrict__ b3,
    const float* __restrict__ w4, const float* __restrict__ u4, const float* __restrict__ b4,
    const float* __restrict__ wd, const float* __restrict__ bd,
    float* __restrict__ out, int B)
{
    const int tid = blockIdx.x * 256 + threadIdx.x;
    const int e = tid >> 4;               // batch element = one 16-lane row
    if (e >= B) return;
    const int l16 = tid & 15;
    const int q = l16 >> 2;               // quad = layer index 0..3
    const int u = l16 & 3;                // unit within layer (3 = spare)
    const int uu = (u < 3) ? u : 2;

    const float* Wp = (q == 0) ? w1 : (q == 1) ? w2 : (q == 2) ? w3 : w4;
    const float* Up = (q == 0) ? u1 : (q == 1) ? u2 : (q == 2) ? u3 : u4;
    const float* Bp = (q == 0) ? b1 : (q == 1) ? b2 : (q == 2) ? b3 : b4;
    const int nx = (q == 0) ? 1 : 3;      // input dims of this layer

    // Folded activation scales per gate (i,f,o: -log2e; g: +2*log2e).
    float W[3][4], U[3][4], Bv[4];
#pragma unroll
    for (int g = 0; g < 4; ++g) {
        const float sc = (g == 2) ? (2.0f * LOG2E) : (-LOG2E);
        const int col = g * 3 + uu;       // gate-major columns: (i,f,g,o) x unit
        Bv[g] = Bp[col] * sc;
#pragma unroll
        for (int k = 0; k < 3; ++k) {
            W[k][g] = (k < nx) ? Wp[k * 12 + col] * sc : 0.0f;  // guard w1 OOB
            U[k][g] = Up[k * 12 + col] * sc;
        }
    }

    float h[3]   = {0.f, 0.f, 0.f};       // this quad's hidden state
    float xin[3] = {0.f, 0.f, 0.f};       // input vector from previous quad
    float c = 0.f;

    const float4* sp = reinterpret_cast<const float4*>(state + (size_t)e * 256);

    // --- pipeline fill: n = 0,1,2 (masked), n = 3 (first fully-valid) ---
    float4 w = sp[0];
    step<true >(0, w.x, q, W, U, Bv, h, xin, c);
    step<true >(1, w.y, q, W, U, Bv, h, xin, c);
    step<true >(2, w.z, q, W, U, Bv, h, xin, c);
    float4 wn = sp[1];                    // prefetch word 1
    step<false>(3, w.w, q, W, U, Bv, h, xin, c);
    w = wn;

    // --- main loop: words 1..62, prefetch one word ahead ---
    for (int g4 = 1; g4 < 63; ++g4) {
        wn = sp[g4 + 1];
        step<false>(0, w.x, q, W, U, Bv, h, xin, c);
        step<false>(0, w.y, q, W, U, Bv, h, xin, c);
        step<false>(0, w.z, q, W, U, Bv, h, xin, c);
        step<false>(0, w.w, q, W, U, Bv, h, xin, c);
        w = wn;
    }
    // --- word 63 (t = 252..255) ---
    step<false>(0, w.x, q, W, U, Bv, h, xin, c);
    step<false>(0, w.y, q, W, U, Bv, h, xin, c);
    step<false>(0, w.z, q, W, U, Bv, h, xin, c);
    step<false>(0, w.w, q, W, U, Bv, h, xin, c);

    // --- drain: n = 256,257,258 — finishes quads 1..3; x forced to 0 ---
    step<false>(0, 0.f, q, W, U, Bv, h, xin, c);
    step<false>(0, 0.f, q, W, U, Bv, h, xin, c);
    step<false>(0, 0.f, q, W, U, Bv, h, xin, c);

    // Dense(1): quad 3 holds final h4 (broadcast across its lanes).
    if (l16 == 12) {
        out[e] = fmaf(h[0], wd[0], fmaf(h[1], wd[1], fmaf(h[2], wd[2], bd[0])));
    }
}

extern "C" void kernel_launch(void* const* d_in, const int* in_sizes, int n_in,
                              void* d_out, int out_size, void* d_ws, size_t ws_size,
                              hipStream_t stream) {
    const float* state = (const float*)d_in[0];
    const float* w1 = (const float*)d_in[1];
    const float* u1 = (const float*)d_in[2];
    const float* b1 = (const float*)d_in[3];
    const float* w2 = (const float*)d_in[4];
    const float* u2 = (const float*)d_in[5];
    const float* b2 = (const float*)d_in[6];
    const float* w3 = (const float*)d_in[7];
    const float* u3 = (const float*)d_in[8];
    const float* b3 = (const float*)d_in[9];
    const float* w4 = (const float*)d_in[10];
    const float* u4 = (const float*)d_in[11];
    const float* b4 = (const float*)d_in[12];
    const float* wd = (const float*)d_in[13];
    const float* bd = (const float*)d_in[14];
    float* out = (float*)d_out;

    const int B = in_sizes[0] / 256;              // 8192
    const long long threads = (long long)B * 16;  // 16 lanes per element
    const int grid = (int)((threads + 255) / 256);
    lstm_pipe<<<grid, 256, 0, stream>>>(state, w1, u1, b1, w2, u2, b2,
                                        w3, u3, b3, w4, u4, b4, wd, bd, out, B);
}